// Round 1
// baseline (1738.381 us; speedup 1.0000x reference)
//
#include <hip/hip_runtime.h>

// LGCN encoder: 3 layers of (social SpMM on users) + (adjacency SpMM on all nodes),
// accumulated and averaged. All fp32. COO scatter-atomic SpMM, one wave per nnz.

constexpr int USER_NUM = 50000;
constexpr int ITEM_NUM = 50000;
constexpr int N_NODES  = USER_NUM + ITEM_NUM;   // 100000
constexpr int EMB      = 64;
constexpr int N_LAYERS = 3;
constexpr int TOTAL    = N_NODES * EMB;         // 6,400,000 floats
constexpr int TOTAL4   = TOTAL / 4;             // 1,600,000 float4
constexpr int U4       = USER_NUM * EMB / 4;    // 800,000 float4

// ego = concat(user, item); acc = ego
__global__ void init_kernel(const float* __restrict__ user_emb,
                            const float* __restrict__ item_emb,
                            float* __restrict__ ego,
                            float* __restrict__ acc) {
    int i = blockIdx.x * blockDim.x + threadIdx.x;
    if (i >= TOTAL4) return;
    float4 v = (i < U4) ? reinterpret_cast<const float4*>(user_emb)[i]
                        : reinterpret_cast<const float4*>(item_emb)[i - U4];
    reinterpret_cast<float4*>(ego)[i] = v;
    reinterpret_cast<float4*>(acc)[i] = v;
}

// h = ego (copy), next = 0 (for the upcoming scatter)
__global__ void copy_and_zero(const float* __restrict__ ego,
                              float* __restrict__ h,
                              float* __restrict__ next) {
    int i = blockIdx.x * blockDim.x + threadIdx.x;
    if (i >= TOTAL4) return;
    reinterpret_cast<float4*>(h)[i] = reinterpret_cast<const float4*>(ego)[i];
    reinterpret_cast<float4*>(next)[i] = make_float4(0.f, 0.f, 0.f, 0.f);
}

// dst[rows[e], :] += vals[e] * src[cols[e], :]   (one 64-lane wave per nnz)
__global__ void spmm_atomic(const int* __restrict__ rows,
                            const int* __restrict__ cols,
                            const float* __restrict__ vals,
                            const float* __restrict__ src,
                            float* __restrict__ dst,
                            int nnz) {
    int e = blockIdx.x * (blockDim.x >> 6) + (threadIdx.x >> 6);
    if (e >= nnz) return;
    int lane = threadIdx.x & 63;
    int r = rows[e];
    int c = cols[e];
    float v = vals[e];
    float x = src[c * EMB + lane];
    atomicAdd(dst + r * EMB + lane, v * x);
}

// acc += next
__global__ void acc_add(float* __restrict__ acc, const float* __restrict__ next) {
    int i = blockIdx.x * blockDim.x + threadIdx.x;
    if (i >= TOTAL4) return;
    float4 a = reinterpret_cast<float4*>(acc)[i];
    float4 b = reinterpret_cast<const float4*>(next)[i];
    a.x += b.x; a.y += b.y; a.z += b.z; a.w += b.w;
    reinterpret_cast<float4*>(acc)[i] = a;
}

// acc *= 0.25
__global__ void final_scale(float* __restrict__ acc) {
    int i = blockIdx.x * blockDim.x + threadIdx.x;
    if (i >= TOTAL4) return;
    float4 a = reinterpret_cast<float4*>(acc)[i];
    a.x *= 0.25f; a.y *= 0.25f; a.z *= 0.25f; a.w *= 0.25f;
    reinterpret_cast<float4*>(acc)[i] = a;
}

extern "C" void kernel_launch(void* const* d_in, const int* in_sizes, int n_in,
                              void* d_out, int out_size, void* d_ws, size_t ws_size,
                              hipStream_t stream) {
    const float* user_emb = (const float*)d_in[0];
    const float* item_emb = (const float*)d_in[1];
    const int*   adj_rows = (const int*)d_in[2];
    const int*   adj_cols = (const int*)d_in[3];
    const float* adj_vals = (const float*)d_in[4];
    const int*   s_rows   = (const int*)d_in[5];
    const int*   s_cols   = (const int*)d_in[6];
    const float* s_vals   = (const float*)d_in[7];
    const int adj_nnz = in_sizes[2];
    const int s_nnz   = in_sizes[5];

    float* acc  = (float*)d_out;             // accumulator lives in d_out
    float* bufA = (float*)d_ws;              // ego ping
    float* bufB = bufA + TOTAL;              // ego pong
    float* bufH = bufB + TOTAL;              // h = ego + S*ego_u

    const int BLK = 256;
    const int ew_grid = (TOTAL4 + BLK - 1) / BLK;

    float* ego  = bufA;
    float* next = bufB;

    init_kernel<<<ew_grid, BLK, 0, stream>>>(user_emb, item_emb, ego, acc);

    for (int l = 0; l < N_LAYERS; ++l) {
        copy_and_zero<<<ew_grid, BLK, 0, stream>>>(ego, bufH, next);
        // h_u += S * ego_u   (user rows only; S indices < USER_NUM)
        spmm_atomic<<<(s_nnz + 3) / 4, BLK, 0, stream>>>(s_rows, s_cols, s_vals,
                                                         ego, bufH, s_nnz);
        // next = A * h
        spmm_atomic<<<(adj_nnz + 3) / 4, BLK, 0, stream>>>(adj_rows, adj_cols, adj_vals,
                                                           bufH, next, adj_nnz);
        acc_add<<<ew_grid, BLK, 0, stream>>>(acc, next);
        float* t = ego; ego = next; next = t;
    }

    final_scale<<<ew_grid, BLK, 0, stream>>>(acc);
}

// Round 2
// 1302.714 us; speedup vs baseline: 1.3344x; 1.3344x over previous
//
#include <hip/hip_runtime.h>

// LGCN encoder, CSR-gather formulation.
// Per call: build CSR for adj (100k rows) and S (50k rows) via count/scan/scatter
// (amortized over 3 layers), then 3 x [spmm_s (hu = ego_u + S*ego_u),
// spmm_adj (next = A*h, acc += next, final layer *0.25)]. No fp atomics in hot path.

constexpr int USER_NUM = 50000;
constexpr int ITEM_NUM = 50000;
constexpr int N_NODES  = USER_NUM + ITEM_NUM;   // 100000
constexpr int EMB      = 64;
constexpr int N_LAYERS = 3;
constexpr int TOTAL    = N_NODES * EMB;         // 6,400,000 floats
constexpr int TOTAL4   = TOTAL / 4;
constexpr int U4       = USER_NUM * EMB / 4;

__global__ void init_kernel(const float* __restrict__ user_emb,
                            const float* __restrict__ item_emb,
                            float* __restrict__ ego,
                            float* __restrict__ acc) {
    int i = blockIdx.x * blockDim.x + threadIdx.x;
    if (i >= TOTAL4) return;
    float4 v = (i < U4) ? reinterpret_cast<const float4*>(user_emb)[i]
                        : reinterpret_cast<const float4*>(item_emb)[i - U4];
    reinterpret_cast<float4*>(ego)[i] = v;
    reinterpret_cast<float4*>(acc)[i] = v;
}

__global__ void zero_ints(int* __restrict__ a, int n) {
    int i = blockIdx.x * blockDim.x + threadIdx.x;
    if (i < n) a[i] = 0;
}

__global__ void count_rows(const int* __restrict__ rows, int* __restrict__ cnt, int nnz) {
    int i = blockIdx.x * blockDim.x + threadIdx.x;
    if (i < nnz) atomicAdd(&cnt[rows[i]], 1);
}

// Single-block exclusive scan (1024 threads, loop-carried). Writes ptr[0..n] and work[0..n-1].
__global__ void scan_block(const int* __restrict__ cnt, int* __restrict__ ptr,
                           int* __restrict__ work, int n) {
    __shared__ int buf[1024];
    __shared__ int carry;
    if (threadIdx.x == 0) carry = 0;
    __syncthreads();
    for (int base = 0; base < n; base += 1024) {
        int i = base + (int)threadIdx.x;
        int v = (i < n) ? cnt[i] : 0;
        buf[threadIdx.x] = v;
        __syncthreads();
        for (int off = 1; off < 1024; off <<= 1) {
            int t = (threadIdx.x >= (unsigned)off) ? buf[threadIdx.x - off] : 0;
            __syncthreads();
            buf[threadIdx.x] += t;
            __syncthreads();
        }
        int excl = carry + buf[threadIdx.x] - v;
        if (i < n) { ptr[i] = excl; work[i] = excl; }
        __syncthreads();
        if (threadIdx.x == 1023) carry += buf[1023];
        __syncthreads();
    }
    if (threadIdx.x == 0) ptr[n] = carry;
}

__global__ void scatter_csr(const int* __restrict__ rows, const int* __restrict__ cols,
                            const float* __restrict__ vals, int* __restrict__ work,
                            int* __restrict__ ccol, float* __restrict__ cval, int nnz) {
    int i = blockIdx.x * blockDim.x + threadIdx.x;
    if (i >= nnz) return;
    int pos = atomicAdd(&work[rows[i]], 1);
    ccol[pos] = cols[i];
    cval[pos] = vals[i];
}

// hu[r,:] = ego[r,:] + sum_j S[r,j] * ego[j,:]   (one wave per user row)
__global__ void spmm_s(const int* __restrict__ ptr, const int* __restrict__ ccol,
                       const float* __restrict__ cval, const float* __restrict__ ego,
                       float* __restrict__ hu) {
    int r = blockIdx.x * (blockDim.x >> 6) + (threadIdx.x >> 6);
    if (r >= USER_NUM) return;
    int lane = threadIdx.x & 63;
    int beg = ptr[r], end = ptr[r + 1];
    float acc = ego[r * EMB + lane];
    for (int j = beg; j < end; ++j) {
        int c = ccol[j];
        float v = cval[j];
        acc += v * ego[c * EMB + lane];
    }
    hu[r * EMB + lane] = acc;
}

// next[r,:] = sum_j A[r,j] * h[j,:]  where h[j]= (j<USER) ? hu[j] : ego[j]
// acc += next;  on last layer acc = (acc+next)*0.25
__global__ void spmm_adj(const int* __restrict__ ptr, const int* __restrict__ ccol,
                         const float* __restrict__ cval, const float* __restrict__ hu,
                         const float* __restrict__ ego, float* __restrict__ next,
                         float* __restrict__ accbuf, int last) {
    int r = blockIdx.x * (blockDim.x >> 6) + (threadIdx.x >> 6);
    if (r >= N_NODES) return;
    int lane = threadIdx.x & 63;
    int beg = ptr[r], end = ptr[r + 1];
    float acc = 0.f;
    for (int j = beg; j < end; ++j) {
        int c = ccol[j];
        float v = cval[j];
        float x = (c < USER_NUM) ? hu[c * EMB + lane] : ego[c * EMB + lane];
        acc += v * x;
    }
    next[r * EMB + lane] = acc;
    float a = accbuf[r * EMB + lane] + acc;
    if (last) a *= 0.25f;
    accbuf[r * EMB + lane] = a;
}

extern "C" void kernel_launch(void* const* d_in, const int* in_sizes, int n_in,
                              void* d_out, int out_size, void* d_ws, size_t ws_size,
                              hipStream_t stream) {
    const float* user_emb = (const float*)d_in[0];
    const float* item_emb = (const float*)d_in[1];
    const int*   adj_rows = (const int*)d_in[2];
    const int*   adj_cols = (const int*)d_in[3];
    const float* adj_vals = (const float*)d_in[4];
    const int*   s_rows   = (const int*)d_in[5];
    const int*   s_cols   = (const int*)d_in[6];
    const float* s_vals   = (const float*)d_in[7];
    const int adj_nnz = in_sizes[2];
    const int s_nnz   = in_sizes[5];

    float* acc = (float*)d_out;

    char* p = (char*)d_ws;
    auto alloc = [&](size_t bytes) { void* q = p; p += (bytes + 255) & ~(size_t)255; return q; };
    float* egoA  = (float*)alloc((size_t)TOTAL * 4);
    float* egoB  = (float*)alloc((size_t)TOTAL * 4);
    float* hu    = (float*)alloc((size_t)USER_NUM * EMB * 4);
    int*   ptrA  = (int*)alloc((size_t)(N_NODES + 1) * 4);
    int*   workA = (int*)alloc((size_t)N_NODES * 4);
    int*   colA  = (int*)alloc((size_t)adj_nnz * 4);
    float* valA  = (float*)alloc((size_t)adj_nnz * 4);
    int*   ptrS  = (int*)alloc((size_t)(USER_NUM + 1) * 4);
    int*   workS = (int*)alloc((size_t)USER_NUM * 4);
    int*   colS  = (int*)alloc((size_t)s_nnz * 4);
    float* valS  = (float*)alloc((size_t)s_nnz * 4);

    const int BLK = 256;
    const int ew_grid = (TOTAL4 + BLK - 1) / BLK;

    // ---- Build CSR for adj ----
    zero_ints<<<(N_NODES + BLK - 1) / BLK, BLK, 0, stream>>>(workA, N_NODES);
    count_rows<<<(adj_nnz + BLK - 1) / BLK, BLK, 0, stream>>>(adj_rows, workA, adj_nnz);
    scan_block<<<1, 1024, 0, stream>>>(workA, ptrA, workA, N_NODES);
    scatter_csr<<<(adj_nnz + BLK - 1) / BLK, BLK, 0, stream>>>(adj_rows, adj_cols, adj_vals,
                                                               workA, colA, valA, adj_nnz);
    // ---- Build CSR for S ----
    zero_ints<<<(USER_NUM + BLK - 1) / BLK, BLK, 0, stream>>>(workS, USER_NUM);
    count_rows<<<(s_nnz + BLK - 1) / BLK, BLK, 0, stream>>>(s_rows, workS, s_nnz);
    scan_block<<<1, 1024, 0, stream>>>(workS, ptrS, workS, USER_NUM);
    scatter_csr<<<(s_nnz + BLK - 1) / BLK, BLK, 0, stream>>>(s_rows, s_cols, s_vals,
                                                             workS, colS, valS, s_nnz);

    // ---- init ego + acc ----
    init_kernel<<<ew_grid, BLK, 0, stream>>>(user_emb, item_emb, egoA, acc);

    float* ego  = egoA;
    float* next = egoB;
    const int s_grid   = (USER_NUM + 3) / 4;   // 4 waves/block
    const int adj_grid = (N_NODES + 3) / 4;

    for (int l = 0; l < N_LAYERS; ++l) {
        spmm_s<<<s_grid, BLK, 0, stream>>>(ptrS, colS, valS, ego, hu);
        spmm_adj<<<adj_grid, BLK, 0, stream>>>(ptrA, colA, valA, hu, ego, next, acc,
                                               l == N_LAYERS - 1 ? 1 : 0);
        float* t = ego; ego = next; next = t;
    }
}

// Round 3
// 1056.006 us; speedup vs baseline: 1.6462x; 1.2336x over previous
//
#include <hip/hip_runtime.h>

// LGCN encoder, CSR-gather formulation with two-level (multi-block) scan.
// Per call: build CSR for adj (100k rows) and S (50k rows) via count / 2-level
// scan / scatter, then 3 x [spmm_s (hu = ego_u + S*ego_u),
// spmm_adj (next = A*h, acc += next, final layer *0.25)]. No fp atomics.

constexpr int USER_NUM = 50000;
constexpr int ITEM_NUM = 50000;
constexpr int N_NODES  = USER_NUM + ITEM_NUM;   // 100000
constexpr int EMB      = 64;
constexpr int N_LAYERS = 3;
constexpr int TOTAL    = N_NODES * EMB;         // 6,400,000 floats
constexpr int TOTAL4   = TOTAL / 4;
constexpr int U4       = USER_NUM * EMB / 4;

__global__ void init_kernel(const float* __restrict__ user_emb,
                            const float* __restrict__ item_emb,
                            float* __restrict__ ego,
                            float* __restrict__ acc) {
    int i = blockIdx.x * blockDim.x + threadIdx.x;
    if (i >= TOTAL4) return;
    float4 v = (i < U4) ? reinterpret_cast<const float4*>(user_emb)[i]
                        : reinterpret_cast<const float4*>(item_emb)[i - U4];
    reinterpret_cast<float4*>(ego)[i] = v;
    reinterpret_cast<float4*>(acc)[i] = v;
}

__global__ void zero_ints(int* __restrict__ a, int n) {
    int i = blockIdx.x * blockDim.x + threadIdx.x;
    if (i < n) a[i] = 0;
}

__global__ void count_rows(const int* __restrict__ rows, int* __restrict__ cnt, int nnz) {
    int i = blockIdx.x * blockDim.x + threadIdx.x;
    if (i < nnz) atomicAdd(&cnt[rows[i]], 1);
}

// Level 1: each 1024-thread block scans its 1024-chunk (exclusive, no block
// offset) into ptr[], and writes its chunk total to bsum[blockIdx].
__global__ void scan_local(const int* __restrict__ cnt, int* __restrict__ ptr,
                           int* __restrict__ bsum, int n) {
    __shared__ int buf[1024];
    int i = blockIdx.x * 1024 + (int)threadIdx.x;
    int v = (i < n) ? cnt[i] : 0;
    buf[threadIdx.x] = v;
    __syncthreads();
    for (int off = 1; off < 1024; off <<= 1) {
        int t = (threadIdx.x >= (unsigned)off) ? buf[threadIdx.x - off] : 0;
        __syncthreads();
        buf[threadIdx.x] += t;
        __syncthreads();
    }
    if (i < n) ptr[i] = buf[threadIdx.x] - v;   // exclusive within chunk
    if (threadIdx.x == 1023) bsum[blockIdx.x] = buf[1023];
}

// Level 2: one block turns bsum[0..nb-1] into its exclusive scan, writes total
// to ptr[n]. nb <= 1024.
__global__ void scan_bsums(int* __restrict__ bsum, int* __restrict__ ptr,
                           int nb, int n) {
    __shared__ int buf[1024];
    int v = ((int)threadIdx.x < nb) ? bsum[threadIdx.x] : 0;
    buf[threadIdx.x] = v;
    __syncthreads();
    for (int off = 1; off < 1024; off <<= 1) {
        int t = (threadIdx.x >= (unsigned)off) ? buf[threadIdx.x - off] : 0;
        __syncthreads();
        buf[threadIdx.x] += t;
        __syncthreads();
    }
    if ((int)threadIdx.x < nb) bsum[threadIdx.x] = buf[threadIdx.x] - v;
    if (threadIdx.x == 1023) ptr[n] = buf[1023];
}

// Level 3: add block offsets; duplicate into work[] for the scatter pass.
__global__ void add_offsets(int* __restrict__ ptr, const int* __restrict__ bsum,
                            int* __restrict__ work, int n) {
    int i = blockIdx.x * blockDim.x + threadIdx.x;
    if (i >= n) return;
    int val = ptr[i] + bsum[i >> 10];
    ptr[i] = val;
    work[i] = val;
}

__global__ void scatter_csr(const int* __restrict__ rows, const int* __restrict__ cols,
                            const float* __restrict__ vals, int* __restrict__ work,
                            int* __restrict__ ccol, float* __restrict__ cval, int nnz) {
    int i = blockIdx.x * blockDim.x + threadIdx.x;
    if (i >= nnz) return;
    int pos = atomicAdd(&work[rows[i]], 1);
    ccol[pos] = cols[i];
    cval[pos] = vals[i];
}

// hu[r,:] = ego[r,:] + sum_j S[r,j] * ego[j,:]   (one wave per user row)
__global__ void spmm_s(const int* __restrict__ ptr, const int* __restrict__ ccol,
                       const float* __restrict__ cval, const float* __restrict__ ego,
                       float* __restrict__ hu) {
    int r = blockIdx.x * (blockDim.x >> 6) + (threadIdx.x >> 6);
    if (r >= USER_NUM) return;
    int lane = threadIdx.x & 63;
    int beg = ptr[r], end = ptr[r + 1];
    float acc = ego[r * EMB + lane];
    for (int j = beg; j < end; ++j) {
        int c = ccol[j];
        float v = cval[j];
        acc += v * ego[c * EMB + lane];
    }
    hu[r * EMB + lane] = acc;
}

// next[r,:] = sum_j A[r,j] * h[j,:]  where h[j] = (j<USER) ? hu[j] : ego[j]
// acc += next;  on last layer acc = (acc+next)*0.25
__global__ void spmm_adj(const int* __restrict__ ptr, const int* __restrict__ ccol,
                         const float* __restrict__ cval, const float* __restrict__ hu,
                         const float* __restrict__ ego, float* __restrict__ next,
                         float* __restrict__ accbuf, int last) {
    int r = blockIdx.x * (blockDim.x >> 6) + (threadIdx.x >> 6);
    if (r >= N_NODES) return;
    int lane = threadIdx.x & 63;
    int beg = ptr[r], end = ptr[r + 1];
    float acc = 0.f;
    for (int j = beg; j < end; ++j) {
        int c = ccol[j];
        float v = cval[j];
        float x = (c < USER_NUM) ? hu[c * EMB + lane] : ego[c * EMB + lane];
        acc += v * x;
    }
    next[r * EMB + lane] = acc;
    float a = accbuf[r * EMB + lane] + acc;
    if (last) a *= 0.25f;
    accbuf[r * EMB + lane] = a;
}

extern "C" void kernel_launch(void* const* d_in, const int* in_sizes, int n_in,
                              void* d_out, int out_size, void* d_ws, size_t ws_size,
                              hipStream_t stream) {
    const float* user_emb = (const float*)d_in[0];
    const float* item_emb = (const float*)d_in[1];
    const int*   adj_rows = (const int*)d_in[2];
    const int*   adj_cols = (const int*)d_in[3];
    const float* adj_vals = (const float*)d_in[4];
    const int*   s_rows   = (const int*)d_in[5];
    const int*   s_cols   = (const int*)d_in[6];
    const float* s_vals   = (const float*)d_in[7];
    const int adj_nnz = in_sizes[2];
    const int s_nnz   = in_sizes[5];

    float* acc = (float*)d_out;

    char* p = (char*)d_ws;
    auto alloc = [&](size_t bytes) { void* q = p; p += (bytes + 255) & ~(size_t)255; return q; };
    float* egoA  = (float*)alloc((size_t)TOTAL * 4);
    float* egoB  = (float*)alloc((size_t)TOTAL * 4);
    float* hu    = (float*)alloc((size_t)USER_NUM * EMB * 4);
    int*   ptrA  = (int*)alloc((size_t)(N_NODES + 1) * 4);
    int*   workA = (int*)alloc((size_t)N_NODES * 4);
    int*   colA  = (int*)alloc((size_t)adj_nnz * 4);
    float* valA  = (float*)alloc((size_t)adj_nnz * 4);
    int*   ptrS  = (int*)alloc((size_t)(USER_NUM + 1) * 4);
    int*   workS = (int*)alloc((size_t)USER_NUM * 4);
    int*   colS  = (int*)alloc((size_t)s_nnz * 4);
    float* valS  = (float*)alloc((size_t)s_nnz * 4);
    int*   bsumA = (int*)alloc(1024 * 4);
    int*   bsumS = (int*)alloc(1024 * 4);

    const int BLK = 256;
    const int ew_grid = (TOTAL4 + BLK - 1) / BLK;
    const int nbA = (N_NODES + 1023) / 1024;    // 98
    const int nbS = (USER_NUM + 1023) / 1024;   // 49

    // ---- Build CSR for adj ----
    zero_ints<<<(N_NODES + BLK - 1) / BLK, BLK, 0, stream>>>(workA, N_NODES);
    count_rows<<<(adj_nnz + BLK - 1) / BLK, BLK, 0, stream>>>(adj_rows, workA, adj_nnz);
    scan_local<<<nbA, 1024, 0, stream>>>(workA, ptrA, bsumA, N_NODES);
    scan_bsums<<<1, 1024, 0, stream>>>(bsumA, ptrA, nbA, N_NODES);
    add_offsets<<<(N_NODES + BLK - 1) / BLK, BLK, 0, stream>>>(ptrA, bsumA, workA, N_NODES);
    scatter_csr<<<(adj_nnz + BLK - 1) / BLK, BLK, 0, stream>>>(adj_rows, adj_cols, adj_vals,
                                                               workA, colA, valA, adj_nnz);
    // ---- Build CSR for S ----
    zero_ints<<<(USER_NUM + BLK - 1) / BLK, BLK, 0, stream>>>(workS, USER_NUM);
    count_rows<<<(s_nnz + BLK - 1) / BLK, BLK, 0, stream>>>(s_rows, workS, s_nnz);
    scan_local<<<nbS, 1024, 0, stream>>>(workS, ptrS, bsumS, USER_NUM);
    scan_bsums<<<1, 1024, 0, stream>>>(bsumS, ptrS, nbS, USER_NUM);
    add_offsets<<<(USER_NUM + BLK - 1) / BLK, BLK, 0, stream>>>(ptrS, bsumS, workS, USER_NUM);
    scatter_csr<<<(s_nnz + BLK - 1) / BLK, BLK, 0, stream>>>(s_rows, s_cols, s_vals,
                                                             workS, colS, valS, s_nnz);

    // ---- init ego + acc ----
    init_kernel<<<ew_grid, BLK, 0, stream>>>(user_emb, item_emb, egoA, acc);

    float* ego  = egoA;
    float* next = egoB;
    const int s_grid   = (USER_NUM + 3) / 4;   // 4 waves/block
    const int adj_grid = (N_NODES + 3) / 4;

    for (int l = 0; l < N_LAYERS; ++l) {
        spmm_s<<<s_grid, BLK, 0, stream>>>(ptrS, colS, valS, ego, hu);
        spmm_adj<<<adj_grid, BLK, 0, stream>>>(ptrA, colA, valA, hu, ego, next, acc,
                                               l == N_LAYERS - 1 ? 1 : 0);
        float* t = ego; ego = next; next = t;
    }
}

// Round 4
// 706.302 us; speedup vs baseline: 2.4612x; 1.4951x over previous
//
#include <hip/hip_runtime.h>

// LGCN encoder, CSR-gather SpMM with 16-lane-per-row float4 gathers (4 nnz in
// flight per wave), packed (col,val) int2 stream, and pair-fused CSR build.

constexpr int USER_NUM = 50000;
constexpr int ITEM_NUM = 50000;
constexpr int N_NODES  = USER_NUM + ITEM_NUM;   // 100000
constexpr int EMB      = 64;
constexpr int EMB4     = EMB / 4;               // 16
constexpr int N_LAYERS = 3;
constexpr int TOTAL    = N_NODES * EMB;         // 6,400,000 floats
constexpr int TOTAL4   = TOTAL / 4;
constexpr int U4       = USER_NUM * EMB / 4;

__global__ void init_kernel(const float* __restrict__ user_emb,
                            const float* __restrict__ item_emb,
                            float* __restrict__ ego,
                            float* __restrict__ acc) {
    int i = blockIdx.x * blockDim.x + threadIdx.x;
    if (i >= TOTAL4) return;
    float4 v = (i < U4) ? reinterpret_cast<const float4*>(user_emb)[i]
                        : reinterpret_cast<const float4*>(item_emb)[i - U4];
    reinterpret_cast<float4*>(ego)[i] = v;
    reinterpret_cast<float4*>(acc)[i] = v;
}

// zero both row-count arrays in one launch
__global__ void zero2(int* __restrict__ a, int na, int* __restrict__ b, int nb) {
    int i = blockIdx.x * blockDim.x + threadIdx.x;
    if (i < na) a[i] = 0;
    if (i < nb) b[i] = 0;
}

// histogram both matrices in one launch
__global__ void count2(const int* __restrict__ arows, int annz, int* __restrict__ acnt,
                       const int* __restrict__ srows, int snnz, int* __restrict__ scnt) {
    int i = blockIdx.x * blockDim.x + threadIdx.x;
    if (i < annz) atomicAdd(&acnt[arows[i]], 1);
    else if (i - annz < snnz) atomicAdd(&scnt[srows[i - annz]], 1);
}

// Level 1 scan for both matrices: blocks [0,nbA) -> A, [nbA,nbA+nbS) -> S.
__global__ void scan_local2(const int* __restrict__ cntA, int* __restrict__ ptrA,
                            int* __restrict__ bsumA, int nA, int nbA,
                            const int* __restrict__ cntS, int* __restrict__ ptrS,
                            int* __restrict__ bsumS, int nS) {
    __shared__ int buf[1024];
    const int* cnt; int* ptr; int* bsum; int n; int b;
    if ((int)blockIdx.x < nbA) { cnt = cntA; ptr = ptrA; bsum = bsumA; n = nA; b = blockIdx.x; }
    else                       { cnt = cntS; ptr = ptrS; bsum = bsumS; n = nS; b = blockIdx.x - nbA; }
    int i = b * 1024 + (int)threadIdx.x;
    int v = (i < n) ? cnt[i] : 0;
    buf[threadIdx.x] = v;
    __syncthreads();
    for (int off = 1; off < 1024; off <<= 1) {
        int t = (threadIdx.x >= (unsigned)off) ? buf[threadIdx.x - off] : 0;
        __syncthreads();
        buf[threadIdx.x] += t;
        __syncthreads();
    }
    if (i < n) ptr[i] = buf[threadIdx.x] - v;
    if (threadIdx.x == 1023) bsum[b] = buf[1023];
}

// Level 2: block 0 scans A's block sums, block 1 scans S's.
__global__ void scan_bsums2(int* __restrict__ bsumA, int* __restrict__ ptrA, int nbA, int nA,
                            int* __restrict__ bsumS, int* __restrict__ ptrS, int nbS, int nS) {
    __shared__ int buf[1024];
    int* bsum; int* ptr; int nb; int n;
    if (blockIdx.x == 0) { bsum = bsumA; ptr = ptrA; nb = nbA; n = nA; }
    else                 { bsum = bsumS; ptr = ptrS; nb = nbS; n = nS; }
    int v = ((int)threadIdx.x < nb) ? bsum[threadIdx.x] : 0;
    buf[threadIdx.x] = v;
    __syncthreads();
    for (int off = 1; off < 1024; off <<= 1) {
        int t = (threadIdx.x >= (unsigned)off) ? buf[threadIdx.x - off] : 0;
        __syncthreads();
        buf[threadIdx.x] += t;
        __syncthreads();
    }
    if ((int)threadIdx.x < nb) bsum[threadIdx.x] = buf[threadIdx.x] - v;
    if (threadIdx.x == 1023) ptr[n] = buf[1023];
}

// Level 3: add block offsets for both, duplicate into work[].
__global__ void add_offsets2(int* __restrict__ ptrA, const int* __restrict__ bsumA,
                             int* __restrict__ workA, int nA,
                             int* __restrict__ ptrS, const int* __restrict__ bsumS,
                             int* __restrict__ workS, int nS) {
    int i = blockIdx.x * blockDim.x + threadIdx.x;
    if (i < nA) { int v = ptrA[i] + bsumA[i >> 10]; ptrA[i] = v; workA[i] = v; }
    if (i < nS) { int v = ptrS[i] + bsumS[i >> 10]; ptrS[i] = v; workS[i] = v; }
}

// scatter both matrices into packed (col, val_bits) int2 CSR arrays
__global__ void scatter2(const int* __restrict__ arows, const int* __restrict__ acols,
                         const float* __restrict__ avals, int annz,
                         int* __restrict__ workA, int2* __restrict__ packA,
                         const int* __restrict__ srows, const int* __restrict__ scols,
                         const float* __restrict__ svals, int snnz,
                         int* __restrict__ workS, int2* __restrict__ packS) {
    int i = blockIdx.x * blockDim.x + threadIdx.x;
    if (i < annz) {
        int pos = atomicAdd(&workA[arows[i]], 1);
        packA[pos] = make_int2(acols[i], __float_as_int(avals[i]));
    } else if (i - annz < snnz) {
        int k = i - annz;
        int pos = atomicAdd(&workS[srows[k]], 1);
        packS[pos] = make_int2(scols[k], __float_as_int(svals[k]));
    }
}

__device__ __forceinline__ float4 group_reduce4(float4 a) {
    // sum across the 4 16-lane groups (lanes differing in bits 4,5)
    for (int m = 16; m < 64; m <<= 1) {
        a.x += __shfl_xor(a.x, m, 64);
        a.y += __shfl_xor(a.y, m, 64);
        a.z += __shfl_xor(a.z, m, 64);
        a.w += __shfl_xor(a.w, m, 64);
    }
    return a;
}

// hu[r,:] = ego[r,:] + sum_j S[r,j] * ego[j,:]
// one wave per row; 16 lanes x float4 per gather; 4 nnz in flight
__global__ void spmm_s(const int* __restrict__ ptr, const int2* __restrict__ pack,
                       const float* __restrict__ ego, float* __restrict__ hu) {
    int r = blockIdx.x * (blockDim.x >> 6) + (threadIdx.x >> 6);
    if (r >= USER_NUM) return;
    int lane = threadIdx.x & 63;
    int g = lane >> 4, li = lane & 15;
    int beg = ptr[r], end = ptr[r + 1];
    const float4* ego4 = reinterpret_cast<const float4*>(ego);
    float4 acc = make_float4(0.f, 0.f, 0.f, 0.f);
    for (int j = beg + g; j < end; j += 4) {
        int2 p = pack[j];
        float v = __int_as_float(p.y);
        float4 x = ego4[p.x * EMB4 + li];
        acc.x += v * x.x; acc.y += v * x.y; acc.z += v * x.z; acc.w += v * x.w;
    }
    acc = group_reduce4(acc);
    if (g == 0) {
        float4 e = ego4[r * EMB4 + li];
        acc.x += e.x; acc.y += e.y; acc.z += e.z; acc.w += e.w;
        reinterpret_cast<float4*>(hu)[r * EMB4 + li] = acc;
    }
}

// next[r,:] = sum_j A[r,j] * h[j,:], h[j] = (j<USER)? hu[j] : ego[j]
// acc += next; last layer: acc = (acc+next)*0.25
__global__ void spmm_adj(const int* __restrict__ ptr, const int2* __restrict__ pack,
                         const float* __restrict__ hu, const float* __restrict__ ego,
                         float* __restrict__ next, float* __restrict__ accbuf, int last) {
    int r = blockIdx.x * (blockDim.x >> 6) + (threadIdx.x >> 6);
    if (r >= N_NODES) return;
    int lane = threadIdx.x & 63;
    int g = lane >> 4, li = lane & 15;
    int beg = ptr[r], end = ptr[r + 1];
    const float4* ego4 = reinterpret_cast<const float4*>(ego);
    const float4* hu4  = reinterpret_cast<const float4*>(hu);
    float4 acc = make_float4(0.f, 0.f, 0.f, 0.f);
    for (int j = beg + g; j < end; j += 4) {
        int2 p = pack[j];
        float v = __int_as_float(p.y);
        float4 x = (p.x < USER_NUM) ? hu4[p.x * EMB4 + li] : ego4[p.x * EMB4 + li];
        acc.x += v * x.x; acc.y += v * x.y; acc.z += v * x.z; acc.w += v * x.w;
    }
    acc = group_reduce4(acc);
    if (g == 0) {
        reinterpret_cast<float4*>(next)[r * EMB4 + li] = acc;
        float4 a = reinterpret_cast<float4*>(accbuf)[r * EMB4 + li];
        a.x += acc.x; a.y += acc.y; a.z += acc.z; a.w += acc.w;
        if (last) { a.x *= 0.25f; a.y *= 0.25f; a.z *= 0.25f; a.w *= 0.25f; }
        reinterpret_cast<float4*>(accbuf)[r * EMB4 + li] = a;
    }
}

extern "C" void kernel_launch(void* const* d_in, const int* in_sizes, int n_in,
                              void* d_out, int out_size, void* d_ws, size_t ws_size,
                              hipStream_t stream) {
    const float* user_emb = (const float*)d_in[0];
    const float* item_emb = (const float*)d_in[1];
    const int*   adj_rows = (const int*)d_in[2];
    const int*   adj_cols = (const int*)d_in[3];
    const float* adj_vals = (const float*)d_in[4];
    const int*   s_rows   = (const int*)d_in[5];
    const int*   s_cols   = (const int*)d_in[6];
    const float* s_vals   = (const float*)d_in[7];
    const int adj_nnz = in_sizes[2];
    const int s_nnz   = in_sizes[5];

    float* acc = (float*)d_out;

    char* p = (char*)d_ws;
    auto alloc = [&](size_t bytes) { void* q = p; p += (bytes + 255) & ~(size_t)255; return q; };
    float* egoA  = (float*)alloc((size_t)TOTAL * 4);
    float* egoB  = (float*)alloc((size_t)TOTAL * 4);
    float* hu    = (float*)alloc((size_t)USER_NUM * EMB * 4);
    int*   ptrA  = (int*)alloc((size_t)(N_NODES + 1) * 4);
    int*   workA = (int*)alloc((size_t)N_NODES * 4);
    int2*  packA = (int2*)alloc((size_t)adj_nnz * 8);
    int*   ptrS  = (int*)alloc((size_t)(USER_NUM + 1) * 4);
    int*   workS = (int*)alloc((size_t)USER_NUM * 4);
    int2*  packS = (int2*)alloc((size_t)s_nnz * 8);
    int*   bsumA = (int*)alloc(1024 * 4);
    int*   bsumS = (int*)alloc(1024 * 4);

    const int BLK = 256;
    const int ew_grid = (TOTAL4 + BLK - 1) / BLK;
    const int nbA = (N_NODES + 1023) / 1024;    // 98
    const int nbS = (USER_NUM + 1023) / 1024;   // 49

    // ---- fused CSR build for adj + S ----
    zero2<<<(N_NODES + BLK - 1) / BLK, BLK, 0, stream>>>(workA, N_NODES, workS, USER_NUM);
    count2<<<(adj_nnz + s_nnz + BLK - 1) / BLK, BLK, 0, stream>>>(adj_rows, adj_nnz, workA,
                                                                  s_rows, s_nnz, workS);
    scan_local2<<<nbA + nbS, 1024, 0, stream>>>(workA, ptrA, bsumA, N_NODES, nbA,
                                                workS, ptrS, bsumS, USER_NUM);
    scan_bsums2<<<2, 1024, 0, stream>>>(bsumA, ptrA, nbA, N_NODES,
                                        bsumS, ptrS, nbS, USER_NUM);
    add_offsets2<<<(N_NODES + BLK - 1) / BLK, BLK, 0, stream>>>(ptrA, bsumA, workA, N_NODES,
                                                                ptrS, bsumS, workS, USER_NUM);
    scatter2<<<(adj_nnz + s_nnz + BLK - 1) / BLK, BLK, 0, stream>>>(
        adj_rows, adj_cols, adj_vals, adj_nnz, workA, packA,
        s_rows, s_cols, s_vals, s_nnz, workS, packS);

    // ---- init ego + acc ----
    init_kernel<<<ew_grid, BLK, 0, stream>>>(user_emb, item_emb, egoA, acc);

    float* ego  = egoA;
    float* next = egoB;
    const int s_grid   = (USER_NUM + 3) / 4;   // 4 waves/block
    const int adj_grid = (N_NODES + 3) / 4;

    for (int l = 0; l < N_LAYERS; ++l) {
        spmm_s<<<s_grid, BLK, 0, stream>>>(ptrS, packS, ego, hu);
        spmm_adj<<<adj_grid, BLK, 0, stream>>>(ptrA, packA, hu, ego, next, acc,
                                               l == N_LAYERS - 1 ? 1 : 0);
        float* t = ego; ego = next; next = t;
    }
}